// Round 2
// baseline (117.128 us; speedup 1.0000x reference)
//
#include <hip/hip_runtime.h>

#define N_BINS 15

// fl(1/15) as fp32 — matches jnp.linspace's step
#define INV15 0.066666670143604278564453125f

__global__ __launch_bounds__(256) void ece_accum(
    const float* __restrict__ logits,
    const int* __restrict__ labels,
    int N,
    float* __restrict__ g_conf,
    unsigned* __restrict__ g_cnt,
    unsigned* __restrict__ g_acc) {

  // Per-thread register accumulators (compile-time indexed only — stays in VGPRs)
  float    conf_s[N_BINS];
  unsigned pk_s[N_BINS];   // (count << 16) | acc
#pragma unroll
  for (int b = 0; b < N_BINS; ++b) { conf_s[b] = 0.0f; pk_s[b] = 0u; }

  const int tid = threadIdx.x;
  const int gid = blockIdx.x * blockDim.x + tid;
  const int stride = gridDim.x * blockDim.x;

  auto process = [&](const float lg[10], const int lb[10]) {
    float mx   = lg[0];
    int   pred = (lg[0] >= 0.0f) ? 0 : -1;  // sigmoid(x) >= 0.5 <=> x >= 0
    int   best = lb[0];
    int   lidx = 0;
#pragma unroll
    for (int j = 1; j < 10; ++j) {
      mx = fmaxf(mx, lg[j]);
      if (pred < 0 && lg[j] >= 0.0f) pred = j;      // first index of mask-max
      if (lb[j] > best) { best = lb[j]; lidx = j; } // first occurrence of max
    }
    if (pred < 0) pred = 0;

    const float conf = 1.0f / (1.0f + __expf(-mx)); // = max(sigmoid(logits))
    const unsigned pkv = (1u << 16) | ((pred == lidx) ? 1u : 0u);

    // smallest b with conf <= (b+1)*INV15 (reference gt/le boundary semantics)
    int bin = N_BINS - 1;
#pragma unroll
    for (int b = N_BINS - 2; b >= 0; --b) {
      if (conf <= (float)(b + 1) * INV15) bin = b;
    }

#pragma unroll
    for (int b = 0; b < N_BINS; ++b) {
      const bool m = (bin == b);
      conf_s[b] += m ? conf : 0.0f;
      pk_s[b]   += m ? pkv : 0u;
    }
  };

  // 2 rows per thread per iteration: 80 B = 5x float4 / 5x int4, 16B-aligned
  const int npairs = N >> 1;
  for (int ip = gid; ip < npairs; ip += stride) {
    const float4* lp = reinterpret_cast<const float4*>(logits) + (size_t)ip * 5;
    const int4*   bp = reinterpret_cast<const int4*>(labels)  + (size_t)ip * 5;
    float4 f0 = lp[0], f1 = lp[1], f2 = lp[2], f3 = lp[3], f4 = lp[4];
    int4   i0 = bp[0], i1 = bp[1], i2 = bp[2], i3 = bp[3], i4 = bp[4];

    {
      float lg[10] = {f0.x,f0.y,f0.z,f0.w,f1.x,f1.y,f1.z,f1.w,f2.x,f2.y};
      int   lb[10] = {i0.x,i0.y,i0.z,i0.w,i1.x,i1.y,i1.z,i1.w,i2.x,i2.y};
      process(lg, lb);
    }
    {
      float lg[10] = {f2.z,f2.w,f3.x,f3.y,f3.z,f3.w,f4.x,f4.y,f4.z,f4.w};
      int   lb[10] = {i2.z,i2.w,i3.x,i3.y,i3.z,i3.w,i4.x,i4.y,i4.z,i4.w};
      process(lg, lb);
    }
  }

  // Odd-N tail (N=4M is even; guard for generality)
  if ((N & 1) && gid == 0) {
    const int i = N - 1;
    float lg[10]; int lb[10];
#pragma unroll
    for (int j = 0; j < 10; ++j) {
      lg[j] = logits[(size_t)i * 10 + j];
      lb[j] = labels[(size_t)i * 10 + j];
    }
    process(lg, lb);
  }

  // Reduction: wave shuffle -> LDS -> global atomics (cold path)
  __shared__ float    s_conf[N_BINS];
  __shared__ unsigned s_pk[N_BINS];
  if (tid < N_BINS) { s_conf[tid] = 0.0f; s_pk[tid] = 0u; }
  __syncthreads();

#pragma unroll
  for (int b = 0; b < N_BINS; ++b) {
    float    c = conf_s[b];
    unsigned p = pk_s[b];
#pragma unroll
    for (int off = 32; off > 0; off >>= 1) {
      c += __shfl_xor(c, off, 64);
      p += (unsigned)__shfl_xor((int)p, off, 64);
    }
    if ((tid & 63) == 0) {   // per-wave: count<=512, acc<=512 -> no field carry
      atomicAdd(&s_conf[b], c);
      atomicAdd(&s_pk[b], p);
    }
  }
  __syncthreads();

  if (tid < N_BINS) {        // per-block: count<=2048 -> still no carry
    atomicAdd(&g_conf[tid], s_conf[tid]);
    atomicAdd(&g_cnt[tid], s_pk[tid] >> 16);
    atomicAdd(&g_acc[tid], s_pk[tid] & 0xFFFFu);
  }
}

__global__ void ece_final(const float* __restrict__ g_conf,
                          const unsigned* __restrict__ g_cnt,
                          const unsigned* __restrict__ g_acc,
                          float* __restrict__ out, int N) {
  if (blockIdx.x == 0 && threadIdx.x == 0) {
    float ece = 0.0f;
    for (int b = 0; b < N_BINS; ++b) {
      const float cnt = (float)g_cnt[b];
      if (cnt > 0.0f) {
        const float safe = fmaxf(cnt, 1.0f);
        const float gap  = fabsf(g_conf[b] / safe - (float)g_acc[b] / safe);
        ece += gap * (cnt / (float)N);
      }
    }
    out[0] = ece;
  }
}

extern "C" void kernel_launch(void* const* d_in, const int* in_sizes, int n_in,
                              void* d_out, int out_size, void* d_ws, size_t ws_size,
                              hipStream_t stream) {
  const float* logits = (const float*)d_in[0];
  const int*   labels = (const int*)d_in[1];
  const int N = in_sizes[0] / 10;  // 4,000,000

  // ws layout: float g_conf[15] | unsigned g_cnt[15] | unsigned g_acc[15]
  float*    g_conf = (float*)d_ws;
  unsigned* g_cnt  = (unsigned*)((char*)d_ws + N_BINS * sizeof(float));
  unsigned* g_acc  = (unsigned*)((char*)d_ws + 2 * N_BINS * sizeof(float));

  hipMemsetAsync(d_ws, 0, 3 * N_BINS * sizeof(float), stream);

  const int block = 256;
  const int grid  = 2048;  // 8 blocks/CU; ~4 pair-iterations per thread
  ece_accum<<<grid, block, 0, stream>>>(logits, labels, N, g_conf, g_cnt, g_acc);
  ece_final<<<1, 64, 0, stream>>>(g_conf, g_cnt, g_acc, (float*)d_out, N);
}

// Round 3
// 106.149 us; speedup vs baseline: 1.1034x; 1.1034x over previous
//
#include <hip/hip_runtime.h>

#define N_BINS 15

// fl(1/15) as fp32 — matches jnp.linspace's step
#define INV15 0.066666670143604278564453125f

// Per wave-chunk: 64 pairs = 128 rows = 320 float4 per matrix = 5120 B
#define PAIRS_PER_CHUNK 64

__global__ __launch_bounds__(256) void ece_accum(
    const float* __restrict__ logits,
    const int* __restrict__ labels,
    int N,
    float* __restrict__ g_conf,
    unsigned* __restrict__ g_cnt,
    unsigned* __restrict__ g_acc) {

  // Per-wave staging: 4 waves x 320 float4 (5120 B) per matrix = 40 KB/block
  __shared__ __align__(16) float s_log[4][1280];
  __shared__ __align__(16) int   s_lab[4][1280];

  // Per-thread register accumulators (compile-time indexed only -> VGPRs)
  float    conf_s[N_BINS];
  unsigned pk_s[N_BINS];   // (count << 16) | acc
#pragma unroll
  for (int b = 0; b < N_BINS; ++b) { conf_s[b] = 0.0f; pk_s[b] = 0u; }

  const int tid  = threadIdx.x;
  const int wid  = tid >> 6;
  const int lane = tid & 63;

  auto process = [&](const float lg[10], const int lb[10]) {
    float mx   = lg[0];
    int   pred = (lg[0] >= 0.0f) ? 0 : -1;  // sigmoid(x) >= 0.5 <=> x >= 0
    int   best = lb[0];
    int   lidx = 0;
#pragma unroll
    for (int j = 1; j < 10; ++j) {
      mx = fmaxf(mx, lg[j]);
      if (pred < 0 && lg[j] >= 0.0f) pred = j;      // first index of mask-max
      if (lb[j] > best) { best = lb[j]; lidx = j; } // first occurrence of max
    }
    if (pred < 0) pred = 0;

    const float conf = 1.0f / (1.0f + __expf(-mx)); // = max(sigmoid(logits))
    const unsigned pkv = (1u << 16) | ((pred == lidx) ? 1u : 0u);

    // smallest b with conf <= (b+1)*INV15 (reference gt/le boundary semantics)
    int bin = N_BINS - 1;
#pragma unroll
    for (int b = N_BINS - 2; b >= 0; --b) {
      if (conf <= (float)(b + 1) * INV15) bin = b;
    }

#pragma unroll
    for (int b = 0; b < N_BINS; ++b) {
      const bool m = (bin == b);
      conf_s[b] += m ? conf : 0.0f;
      pk_s[b]   += m ? pkv : 0u;
    }
  };

  const int npairs  = N >> 1;
  const int nchunks = npairs / PAIRS_PER_CHUNK;               // 31250 for N=4M
  const int gwave   = (blockIdx.x * blockDim.x + tid) >> 6;
  const int nwaves  = (gridDim.x * blockDim.x) >> 6;

  float4* sl = reinterpret_cast<float4*>(s_log[wid]);
  int4*   sb = reinterpret_cast<int4*>(s_lab[wid]);

  for (int c = gwave; c < nchunks; c += nwaves) {
    const float4* Lf = reinterpret_cast<const float4*>(logits) + (size_t)c * 320;
    const int4*   Bf = reinterpret_cast<const int4*>(labels)  + (size_t)c * 320;

    // Coalesced: lane l loads float4 index l + 64k — 1 KiB per instruction
    float4 a0 = Lf[lane], a1 = Lf[lane + 64], a2 = Lf[lane + 128],
           a3 = Lf[lane + 192], a4 = Lf[lane + 256];
    int4   b0 = Bf[lane], b1 = Bf[lane + 64], b2 = Bf[lane + 128],
           b3 = Bf[lane + 192], b4 = Bf[lane + 256];

    // Linear LDS writes (contiguous across lanes -> conflict-free)
    sl[lane] = a0; sl[lane + 64] = a1; sl[lane + 128] = a2;
    sl[lane + 192] = a3; sl[lane + 256] = a4;
    sb[lane] = b0; sb[lane + 64] = b1; sb[lane + 128] = b2;
    sb[lane + 192] = b3; sb[lane + 256] = b4;

    // Per-wave region: wave-synchronous, no __syncthreads needed
    asm volatile("s_waitcnt lgkmcnt(0)" ::: "memory");

    // Lane l reads back its own pair (2 rows, 80 B) at l*80
    const float4* rl = reinterpret_cast<const float4*>(s_log[wid] + lane * 20);
    const int4*   rb = reinterpret_cast<const int4*>(s_lab[wid] + lane * 20);
    float4 f0 = rl[0], f1 = rl[1], f2 = rl[2], f3 = rl[3], f4 = rl[4];
    int4   i0 = rb[0], i1 = rb[1], i2 = rb[2], i3 = rb[3], i4 = rb[4];

    {
      float lg[10] = {f0.x,f0.y,f0.z,f0.w,f1.x,f1.y,f1.z,f1.w,f2.x,f2.y};
      int   lb[10] = {i0.x,i0.y,i0.z,i0.w,i1.x,i1.y,i1.z,i1.w,i2.x,i2.y};
      process(lg, lb);
    }
    {
      float lg[10] = {f2.z,f2.w,f3.x,f3.y,f3.z,f3.w,f4.x,f4.y,f4.z,f4.w};
      int   lb[10] = {i2.z,i2.w,i3.x,i3.y,i3.z,i3.w,i4.x,i4.y,i4.z,i4.w};
      process(lg, lb);
    }
  }

  // Remainder rows not covered by full chunks (0 for N=4M; kept for generality)
  const int done = nchunks * (PAIRS_PER_CHUNK * 2);
  if (blockIdx.x == 0) {
    for (int r = done + tid; r < N; r += blockDim.x) {
      float lg[10]; int lb[10];
#pragma unroll
      for (int j = 0; j < 10; ++j) {
        lg[j] = logits[(size_t)r * 10 + j];
        lb[j] = labels[(size_t)r * 10 + j];
      }
      process(lg, lb);
    }
  }

  // Reduction: wave shuffle -> LDS -> global atomics (cold path)
  __shared__ float    s_conf[N_BINS];
  __shared__ unsigned s_pk[N_BINS];
  __syncthreads();   // staging buffers done; safe to reuse LDS space semantics
  if (tid < N_BINS) { s_conf[tid] = 0.0f; s_pk[tid] = 0u; }
  __syncthreads();

#pragma unroll
  for (int b = 0; b < N_BINS; ++b) {
    float    c = conf_s[b];
    unsigned p = pk_s[b];
#pragma unroll
    for (int off = 32; off > 0; off >>= 1) {
      c += __shfl_xor(c, off, 64);
      p += (unsigned)__shfl_xor((int)p, off, 64);
    }
    if ((tid & 63) == 0) {   // per-wave: count fits 16-bit field easily
      atomicAdd(&s_conf[b], c);
      atomicAdd(&s_pk[b], p);
    }
  }
  __syncthreads();

  if (tid < N_BINS) {
    atomicAdd(&g_conf[tid], s_conf[tid]);
    atomicAdd(&g_cnt[tid], s_pk[tid] >> 16);
    atomicAdd(&g_acc[tid], s_pk[tid] & 0xFFFFu);
  }
}

__global__ void ece_final(const float* __restrict__ g_conf,
                          const unsigned* __restrict__ g_cnt,
                          const unsigned* __restrict__ g_acc,
                          float* __restrict__ out, int N) {
  if (blockIdx.x == 0 && threadIdx.x == 0) {
    float ece = 0.0f;
    for (int b = 0; b < N_BINS; ++b) {
      const float cnt = (float)g_cnt[b];
      if (cnt > 0.0f) {
        const float safe = fmaxf(cnt, 1.0f);
        const float gap  = fabsf(g_conf[b] / safe - (float)g_acc[b] / safe);
        ece += gap * (cnt / (float)N);
      }
    }
    out[0] = ece;
  }
}

extern "C" void kernel_launch(void* const* d_in, const int* in_sizes, int n_in,
                              void* d_out, int out_size, void* d_ws, size_t ws_size,
                              hipStream_t stream) {
  const float* logits = (const float*)d_in[0];
  const int*   labels = (const int*)d_in[1];
  const int N = in_sizes[0] / 10;  // 4,000,000

  // ws layout: float g_conf[15] | unsigned g_cnt[15] | unsigned g_acc[15]
  float*    g_conf = (float*)d_ws;
  unsigned* g_cnt  = (unsigned*)((char*)d_ws + N_BINS * sizeof(float));
  unsigned* g_acc  = (unsigned*)((char*)d_ws + 2 * N_BINS * sizeof(float));

  hipMemsetAsync(d_ws, 0, 3 * N_BINS * sizeof(float), stream);

  const int block = 256;
  const int grid  = 2048;
  ece_accum<<<grid, block, 0, stream>>>(logits, labels, N, g_conf, g_cnt, g_acc);
  ece_final<<<1, 64, 0, stream>>>(g_conf, g_cnt, g_acc, (float*)d_out, N);
}